// Round 7
// baseline (287.680 us; speedup 1.0000x reference)
//
#include <hip/hip_runtime.h>

#define AS1 __attribute__((address_space(1)))
#define AS3 __attribute__((address_space(3)))

typedef short short8 __attribute__((ext_vector_type(8)));
typedef float f32x16 __attribute__((ext_vector_type(16)));
typedef unsigned short ushort4v __attribute__((ext_vector_type(4)));

// Problem constants
#define BATCH 4096
#define IN_F 256
#define OUT_F 256
#define HYP 128
#define HX 129               // HYP + 1 (b2g folded in as extra channel, gain 1.0)
#define KP (HX * IN_F)       // 33024 shorts per V row
#define NBV (OUT_F * HX / 8) // 4128 buildV blocks in k_prep

__device__ __forceinline__ float bf2f(unsigned short u) {
  unsigned v = ((unsigned)u) << 16;
  float f;
  __builtin_memcpy(&f, &v, 4);
  return f;
}
__device__ __forceinline__ unsigned short f2bf(float f) {
  unsigned u;
  __builtin_memcpy(&u, &f, 4);
  unsigned r = u + 0x7fffu + ((u >> 16) & 1u);  // RTNE
  return (unsigned short)(r >> 16);
}

__device__ __forceinline__ void gld_lds16(const unsigned short* g, unsigned short* s) {
  __builtin_amdgcn_global_load_lds((const AS1 unsigned int*)g, (AS3 unsigned int*)s, 16, 0, 0);
}

// ---------------------------------------------------------------------------
// k_prep: merged buildV (blocks 0..NBV-1) + pre (blocks NBV..NBV+255).
// buildV (row-major, r2-proven): V[o][h*256+i] = bf16(h<128 ? W2g[h][o*256+i]
//                                                        : b2g[o*256+i])
// pre: hg -> eps-clamped bf16 transposed [h][b] (+row 128 = 1.0); hb;
//      bias GEMM initializes d_out; x -> bf16.
// ---------------------------------------------------------------------------
__global__ __launch_bounds__(256) void k_prep(const float* __restrict__ x,
                                              const float* __restrict__ W1g, const float* __restrict__ b1g,
                                              const float* __restrict__ W2g, const float* __restrict__ b2g,
                                              const float* __restrict__ W1b, const float* __restrict__ b1b,
                                              const float* __restrict__ W2b, const float* __restrict__ b2b,
                                              unsigned short* __restrict__ Vb,
                                              unsigned short* __restrict__ hgsT,
                                              unsigned short* __restrict__ xb,
                                              float* __restrict__ out) {
  __shared__ float xl[16 * IN_F];                 // 16 KB
  __shared__ float hbl[16 * HYP];                 // 8 KB  [row][h]
  __shared__ unsigned short hgt[HYP * 16];        // 4 KB  [h][row]
  const int t = threadIdx.x;

  if (blockIdx.x < NBV) {
    // ---------------- buildV (row-major) ----------------
    const int cid = blockIdx.x * 256 + t;  // < 256*129*32
    const int ic = cid & 31;
    const int pair = cid >> 5;      // o*129 + h
    const int h = pair % HX;
    const int o = pair / HX;
    const float* src = (h < HYP) ? (W2g + (size_t)h * (OUT_F * IN_F) + o * IN_F + ic * 8)
                                 : (b2g + o * IN_F + ic * 8);
    const float4 v0 = ((const float4*)src)[0];
    const float4 v1 = ((const float4*)src)[1];
    uint4 pk;
    pk.x = (unsigned)f2bf(v0.x) | ((unsigned)f2bf(v0.y) << 16);
    pk.y = (unsigned)f2bf(v0.z) | ((unsigned)f2bf(v0.w) << 16);
    pk.z = (unsigned)f2bf(v1.x) | ((unsigned)f2bf(v1.y) << 16);
    pk.w = (unsigned)f2bf(v1.z) | ((unsigned)f2bf(v1.w) << 16);
    *(uint4*)(Vb + (size_t)o * KP + h * IN_F + ic * 8) = pk;
    return;
  }

  // ---------------- pre ----------------
  const int r0 = (blockIdx.x - NBV) * 16;
  for (int j0 = 0; j0 < 16 * IN_F; j0 += 256) {
    const float v = x[(size_t)r0 * IN_F + j0 + t];
    xl[j0 + t] = v;
    xb[(size_t)r0 * IN_F + j0 + t] = f2bf(v);
  }
  __syncthreads();
  const int h = t & 127;
  const int rb = (t >> 7) * 8;
  float ag[8] = {0.f, 0.f, 0.f, 0.f, 0.f, 0.f, 0.f, 0.f};
  float av[8] = {0.f, 0.f, 0.f, 0.f, 0.f, 0.f, 0.f, 0.f};
  for (int i = 0; i < IN_F; ++i) {
    const float wg = W1g[i * HYP + h];
    const float wb = W1b[i * HYP + h];
#pragma unroll
    for (int r = 0; r < 8; ++r) {
      const float xv = xl[(rb + r) * IN_F + i];
      ag[r] += xv * wg;
      av[r] += xv * wb;
    }
  }
  const float bg = b1g[h], bb = b1b[h];
#pragma unroll
  for (int r = 0; r < 8; ++r) {
    float g = ag[r] + bg; g = g > 0.f ? g : 0.f;
    float v = av[r] + bb; v = v > 0.f ? v : 0.f;
    g = g > 1e-20f ? g : 1e-20f;  // eps-clamp: rescale divides by hg
    hgt[h * 16 + rb + r] = f2bf(g);
    hbl[(rb + r) * HYP + h] = v;
  }
  __syncthreads();
  {  // transposed store: hgsT[h][r0..r0+16)
    const int h2 = t >> 1, part = t & 1;
    const uint4 pk = *(const uint4*)&hgt[h2 * 16 + part * 8];
    *(uint4*)&hgsT[(size_t)h2 * BATCH + r0 + part * 8] = pk;
  }
  if (t < 16) hgsT[(size_t)HYP * BATCH + r0 + t] = 0x3F80;  // row 128 = 1.0
  // out init: out[r0+r][o=t] = b2b + sum_h hb*W2b
  float acc[16];
#pragma unroll
  for (int r = 0; r < 16; ++r) acc[r] = 0.f;
  for (int hh = 0; hh < HYP; ++hh) {
    const float w = W2b[hh * OUT_F + t];
#pragma unroll
    for (int r = 0; r < 16; ++r) acc[r] += hbl[r * HYP + hh] * w;
  }
  const float bo = b2b[t];
#pragma unroll
  for (int r = 0; r < 16; ++r) out[(size_t)(r0 + r) * OUT_F + t] = acc[r] + bo;
}

// ---------------------------------------------------------------------------
// k_gemm: C[b,o] += sum_h hg[b,h] * (x[b,:] . V[o,h,:])
// Tensile-style mega-tile (r2-r6 post-mortem: ALL prior designs needed
// ~31 B/cyc/wave of B delivery = at/over the LDS/L1 pipe -> ~25% plateau):
//   block 256b x 256o, wave tile 128x128 (4x4 of 32x32x16), acc = 256 fp32.
//   (4+4) KB LDS per 16 MFMAs = 15.5 B/cyc/wave; 4 waves -> 63 B/cyc << 128.
// BK=64 (i-dim; h fixed per step, 4 steps per h). A(x) and B(V) both staged
// to LDS via global_load_lds w=16, XOR-swizzled on the source side
// (r2-proven conflict-free), double-buffered, ONE barrier/step; loads get a
// full ~2066-cyc step to land. hg rescale on accumulators at h boundaries
// (every 4th step, broadcast ds_read_b64, ~6% VALU; math validated r3-r6).
// Grid (16 h-chunks, 16 b-tiles) = 256 blocks = 1/CU; grid.x=chunk -> each
// XCD's V slice (2 chunks ~2.2 MB) is L2-resident. 1 wave/SIMD; latency
// hidden by ILP (deep MFMA stream), not TLP.
// Epilogue: per-reg atomicAdd (2x128B segments per instr).
// ---------------------------------------------------------------------------
__global__ __launch_bounds__(256, 1) void k_gemm(const unsigned short* __restrict__ Vb,
                                                 const unsigned short* __restrict__ hgsT,
                                                 const unsigned short* __restrict__ xb,
                                                 float* __restrict__ out) {
  // A bufs [0,32768), B bufs [32768,65536), hg [65536, 65536+9*256)
  __shared__ __align__(16) unsigned short smem[67840];  // 135,680 B
  unsigned short* hgl = smem + 65536;

  const int tid = threadIdx.x;
  const int lane = tid & 63;
  const int wave = tid >> 6;
  const int l31 = lane & 31;
  const int hi = lane >> 5;
  const int wb = (wave & 1) * 128;    // wave b-offset within block
  const int wo = (wave >> 1) * 128;   // wave o-offset within block
  const int chunk = blockIdx.x;
  const int b0 = blockIdx.y * 256;
  const int h0 = chunk * 8;
  const int nh = (chunk == 15) ? 9 : 8;
  const int nsteps = nh * 4;          // 32 or 36

  // ---- staging geometry (per thread: 8 A-chunks + 8 B-chunks of 16B) ----
  // chunk c = j*256 + tid -> row = j*32 + (tid>>3), pos = tid&7,
  // src chunk = pos ^ (row&7)  (row&7 == (tid>>3)&7, j-invariant)
  const int trow = tid >> 3;
  const int tsp = (tid & 7) ^ (trow & 7);
  const unsigned short* xsrc0 = xb + (size_t)(b0 + trow) * IN_F + tsp * 8;
  const unsigned short* vsrc0 = Vb + (size_t)trow * KP + tsp * 8;

  auto stageA = [&](int s, int par) {
    const unsigned short* src = xsrc0 + (s & 3) * 64;
    unsigned short* dst = smem + par * 16384 + tid * 8;
#pragma unroll
    for (int j = 0; j < 8; ++j)
      gld_lds16(src + (size_t)j * (32 * IN_F), dst + j * 2048);
  };
  auto stageB = [&](int s, int par) {
    const unsigned short* src = vsrc0 + (size_t)(h0 + (s >> 2)) * IN_F + (s & 3) * 64;
    unsigned short* dst = smem + 32768 + par * 16384 + tid * 8;
#pragma unroll
    for (int j = 0; j < 8; ++j)
      gld_lds16(src + (size_t)j * (32 * KP), dst + j * 2048);
  };

  // prologue: stage step 0 + hg tile
  stageA(0, 0);
  stageB(0, 0);
  for (int c = tid; c < nh * 32; c += 256) {
    const int hl = c >> 5, cc = c & 31;
    *(uint4*)&hgl[hl * 256 + cc * 8] =
        *(const uint4*)&hgsT[(size_t)(h0 + hl) * BATCH + b0 + cc * 8];
  }
  __syncthreads();

  f32x16 acc[4][4];
#pragma unroll
  for (int ms = 0; ms < 4; ++ms)
#pragma unroll
    for (int ns = 0; ns < 4; ++ns)
#pragma unroll
      for (int g = 0; g < 16; ++g) acc[ms][ns][g] = 0.0f;

  for (int s = 0; s < nsteps; ++s) {
    const int par = s & 1;
    if (s + 1 < nsteps) {  // stage next step into other buffers
      stageA(s + 1, par ^ 1);
      stageB(s + 1, par ^ 1);
    }
    const char* Ab = (const char*)(smem + par * 16384) + wb * 128;
    const char* Bb = (const char*)(smem + 32768 + par * 16384) + wo * 128;
#pragma unroll
    for (int kk = 0; kk < 4; ++kk) {
      const int slot = (kk * 2 + hi) ^ (l31 & 7);
      short8 af[4], bf[4];
#pragma unroll
      for (int ms = 0; ms < 4; ++ms) {
        af[ms] = *(const short8*)(Ab + ms * 4096 + l31 * 128 + slot * 16);
        bf[ms] = *(const short8*)(Bb + ms * 4096 + l31 * 128 + slot * 16);
      }
#pragma unroll
      for (int ms = 0; ms < 4; ++ms)
#pragma unroll
        for (int ns = 0; ns < 4; ++ns)
          acc[ms][ns] = __builtin_amdgcn_mfma_f32_32x32x16_bf16(af[ms], bf[ns], acc[ms][ns], 0, 0, 0);
    }
    if ((s & 3) == 3 && s + 1 < nsteps) {
      // h boundary: acc *= hg[h]/hg[h+1]  (keeps acc in units of 1/hg[cur])
      const int hl = s >> 2;
#pragma unroll
      for (int ms = 0; ms < 4; ++ms) {
#pragma unroll
        for (int q = 0; q < 4; ++q) {
          const int ro = wb + ms * 32 + q * 8 + 4 * hi;
          const ushort4v o4 = *(const ushort4v*)&hgl[hl * 256 + ro];
          const ushort4v n4 = *(const ushort4v*)&hgl[(hl + 1) * 256 + ro];
#pragma unroll
          for (int e = 0; e < 4; ++e) {
            const float rt = bf2f(o4[e]) * __builtin_amdgcn_rcpf(bf2f(n4[e]));
#pragma unroll
            for (int ns = 0; ns < 4; ++ns) acc[ms][ns][q * 4 + e] *= rt;
          }
        }
      }
    }
    __syncthreads();  // buf swap guard; drains next-step staging (1 step old)
  }

  // final scale: acc *= hg[last h of chunk]
  {
    const int hl = nh - 1;
#pragma unroll
    for (int ms = 0; ms < 4; ++ms) {
#pragma unroll
      for (int q = 0; q < 4; ++q) {
        const int ro = wb + ms * 32 + q * 8 + 4 * hi;
        const ushort4v f4 = *(const ushort4v*)&hgl[hl * 256 + ro];
#pragma unroll
        for (int e = 0; e < 4; ++e) {
          const float fv = bf2f(f4[e]);
#pragma unroll
          for (int ns = 0; ns < 4; ++ns) acc[ms][ns][q * 4 + e] *= fv;
        }
      }
    }
  }

  // epilogue: atomic accumulate (16 h-chunk partials per output)
#pragma unroll
  for (int ms = 0; ms < 4; ++ms)
#pragma unroll
    for (int q = 0; q < 4; ++q)
#pragma unroll
      for (int e = 0; e < 4; ++e) {
        const int row = b0 + wb + ms * 32 + q * 8 + 4 * hi + e;
#pragma unroll
        for (int ns = 0; ns < 4; ++ns)
          atomicAdd(&out[(size_t)row * OUT_F + wo + ns * 32 + l31],
                    acc[ms][ns][q * 4 + e]);
      }
}

// ---------------------------------------------------------------------------
extern "C" void kernel_launch(void* const* d_in, const int* in_sizes, int n_in,
                              void* d_out, int out_size, void* d_ws, size_t ws_size,
                              hipStream_t stream) {
  const float* x = (const float*)d_in[0];
  const float* W1g = (const float*)d_in[1];
  const float* b1g = (const float*)d_in[2];
  const float* W2g = (const float*)d_in[3];
  const float* b2g = (const float*)d_in[4];
  const float* W1b = (const float*)d_in[5];
  const float* b1b = (const float*)d_in[6];
  const float* W2b = (const float*)d_in[7];
  const float* b2b = (const float*)d_in[8];
  float* out = (float*)d_out;

  char* ws = (char*)d_ws;
  const size_t szV = (size_t)OUT_F * KP * 2;        // 16,908,288 B
  const size_t szHg = (size_t)HX * BATCH * 2;       //  1,056,768 B (129 rows)
  unsigned short* Vb = (unsigned short*)ws;
  unsigned short* hgsT = (unsigned short*)(ws + szV);
  unsigned short* xb = (unsigned short*)(ws + szV + szHg);

  hipLaunchKernelGGL(k_prep, dim3(NBV + BATCH / 16), dim3(256), 0, stream,
                     x, W1g, b1g, W2g, b2g, W1b, b1b, W2b, b2b, Vb, hgsT, xb, out);
  hipLaunchKernelGGL(k_gemm, dim3(16, BATCH / 256), dim3(256), 0, stream,
                     Vb, hgsT, xb, out);
}